// Round 8
// baseline (63.808 us; speedup 1.0000x reference)
//
#include <hip/hip_runtime.h>
#include <stdint.h>

#define N_NODES 100000
#define N_EDGES 1600000
#define IN_DIM 128
#define OUT_DIM 64

typedef __bf16    bf16x8 __attribute__((ext_vector_type(8)));
typedef float     f32x4  __attribute__((ext_vector_type(4)));

__device__ __forceinline__ uint16_t f2bf(float f) {   // RNE
    uint32_t u = __float_as_uint(f);
    return (uint16_t)((u + 0x7fffu + ((u >> 16) & 1u)) >> 16);
}
__device__ __forceinline__ int dot4i8(uint32_t a, uint32_t b, int c) {
#if __has_builtin(__builtin_amdgcn_sdot4)
    return __builtin_amdgcn_sdot4((int)a, (int)b, c, false);
#else
    #pragma unroll
    for (int k = 0; k < 4; ++k)
        c += (int)(int8_t)(a >> (8 * k)) * (int)(int8_t)(b >> (8 * k));
    return c;
#endif
}

// ---------------------------------------------------------------------------
// prep: blocks [0,6250) build row_ptr from sorted edge_src (O(N+E));
//       blocks [6250,6254) pack W into per-lane MFMA B-fragments.
// ---------------------------------------------------------------------------
__global__ __launch_bounds__(256) void prep(const int* __restrict__ src,
                                            const float* __restrict__ W,
                                            int* __restrict__ row_ptr,
                                            uint4* __restrict__ Wfrag) {
    const int b = blockIdx.x;
    if (b < N_EDGES / 256) {
        int e = b * 256 + threadIdx.x;
        int s = src[e];
        if (e == 0) {
            for (int i = 0; i <= s; ++i) row_ptr[i] = 0;
        } else {
            int sp = src[e - 1];
            for (int i = sp + 1; i <= s; ++i) row_ptr[i] = e;
        }
        if (e == N_EDGES - 1) {
            for (int i = s + 1; i <= N_NODES; ++i) row_ptr[i] = N_EDGES;
        }
    } else {
        int item = (b - N_EDGES / 256) * 256 + threadIdx.x;   // 0..1023
        if (item < 1024) {
            int f = item >> 6, lane = item & 63;
            int ct = f >> 2, ks = f & 3;
            int col = ct * 16 + (lane & 15);
            int kb  = ks * 32 + (lane >> 4) * 8;
            uint32_t u[4];
            #pragma unroll
            for (int j = 0; j < 4; ++j) {
                uint32_t lo = f2bf(W[(kb + 2 * j)     * OUT_DIM + col]);
                uint32_t hi = f2bf(W[(kb + 2 * j + 1) * OUT_DIM + col]);
                u[j] = lo | (hi << 16);
            }
            Wfrag[f * 64 + lane] = make_uint4(u[0], u[1], u[2], u[3]);
        }
    }
}

// ---------------------------------------------------------------------------
// GEMM + fused per-row int8 quantization. X@W via mfma_f32_16x16x32_bf16;
// wave owns 16 rows x all 64 cols. Epilogue: per-row max via 16-lane
// shfl_xor reduce (no global sync!), Q[row] = int8(acc * 127/rowmax),
// scales[row] = rowmax/127. Eliminates XPh + reduce + quantize kernels.
// ---------------------------------------------------------------------------
__global__ __launch_bounds__(256) void gemm_q(const float* __restrict__ X,
                                              const uint4* __restrict__ Wfrag,
                                              uint8_t* __restrict__ Q,
                                              float* __restrict__ scales,
                                              int nRows) {
    const int t = threadIdx.x;
    const int lane = t & 63;

    bf16x8 bfr[16];
    #pragma unroll
    for (int f = 0; f < 16; ++f)
        bfr[f] = __builtin_bit_cast(bf16x8, Wfrag[f * 64 + lane]);

    const int rowBase = blockIdx.x * 64 + (t >> 6) * 16;
    const int r  = rowBase + (lane & 15);
    const int kb = (lane >> 4) * 8;
    const bool inb = r < nRows;

    f32x4 acc[4] = {{0,0,0,0},{0,0,0,0},{0,0,0,0},{0,0,0,0}};

    #pragma unroll
    for (int ks = 0; ks < 4; ++ks) {
        float4 x0 = make_float4(0.f,0.f,0.f,0.f), x1 = x0;
        if (inb) {
            const float* p = &X[(size_t)r * IN_DIM + ks * 32 + kb];
            x0 = *(const float4*)&p[0];
            x1 = *(const float4*)&p[4];
        }
        bf16x8 a;
        a[0]=(__bf16)x0.x; a[1]=(__bf16)x0.y; a[2]=(__bf16)x0.z; a[3]=(__bf16)x0.w;
        a[4]=(__bf16)x1.x; a[5]=(__bf16)x1.y; a[6]=(__bf16)x1.z; a[7]=(__bf16)x1.w;
        #pragma unroll
        for (int ct = 0; ct < 4; ++ct)
            acc[ct] = __builtin_amdgcn_mfma_f32_16x16x32_bf16(a, bfr[ct * 4 + ks], acc[ct], 0, 0, 0);
    }

    // Epilogue. C/D layout: col = ct*16 + (lane&15), row = orow + rr.
    const int orow = rowBase + (lane >> 4) * 4;
    const int ocol = lane & 15;
    #pragma unroll
    for (int rr = 0; rr < 4; ++rr) {
        float m = fmaxf(fmaxf(fabsf(acc[0][rr]), fabsf(acc[1][rr])),
                        fmaxf(fabsf(acc[2][rr]), fabsf(acc[3][rr])));
        m = fmaxf(m, __shfl_xor(m, 1));
        m = fmaxf(m, __shfl_xor(m, 2));
        m = fmaxf(m, __shfl_xor(m, 4));
        m = fmaxf(m, __shfl_xor(m, 8));       // row max over 16 lanes
        const float inv = m > 0.f ? 127.f / m : 0.f;
        const int gr = orow + rr;
        if (gr < nRows) {
            if (ocol == 0) scales[gr] = m * (1.f / 127.f);
            #pragma unroll
            for (int ct = 0; ct < 4; ++ct) {
                int v = (int)rintf(acc[ct][rr] * inv);
                v = min(127, max(-127, v));
                Q[(size_t)gr * OUT_DIM + ct * 16 + ocol] = (uint8_t)(int8_t)v;
            }
        }
    }
}

// ---------------------------------------------------------------------------
// Edge kernel (int8, per-row scales): one NODE per 8-lane group; row = 64B =
// one cache line (8B/lane). Per 8-edge chunk: ONE coalesced dst load per
// group, indices distributed via shfl; gathers exec-mask-guarded (j < nj) so
// finished groups issue NO memory traffic (R7 clamped loads wasted ~2x bytes).
// out = aw * s_i * sum_e pint_e * s_j^2 * q_j  (single final scale).
// ---------------------------------------------------------------------------
__global__ __launch_bounds__(256, 8) void agnn_edge_q(const uint8_t* __restrict__ Q,
                                                      const float* __restrict__ scales,
                                                      const int* __restrict__ row_ptr,
                                                      const int* __restrict__ dst,
                                                      const float* __restrict__ aw,
                                                      float* __restrict__ out) {
    const int t    = threadIdx.x;
    const int lane = t & 63;
    const int g    = lane >> 3;
    const int sl   = lane & 7;
    const int node = blockIdx.x * 32 + (t >> 6) * 8 + g;

    const int lo = row_ptr[node];
    const int hi = row_ptr[node + 1];

    const uint2 q = *(const uint2*)&Q[(size_t)node * OUT_DIM + sl * 8];
    float acc[8] = {0.f,0.f,0.f,0.f,0.f,0.f,0.f,0.f};

    int base = lo;
    while (__any(base < hi)) {
        const int nj = hi - base;              // group-uniform; <=0 when done
        int myd = 0;
        if (base < hi) myd = dst[min(base + sl, hi - 1)];   // coalesced

        uint2 x[8];
        float s2[8];
        #pragma unroll
        for (int j = 0; j < 8; ++j) {
            x[j]  = make_uint2(0u, 0u);
            s2[j] = 0.f;
            if (j < nj) {                       // exec-masked: no mem traffic
                const int dj = __shfl(myd, g * 8 + j);
                x[j] = *(const uint2*)&Q[(size_t)dj * OUT_DIM + sl * 8];
                const float sj = scales[dj];
                s2[j] = sj * sj;
            }
        }
        #pragma unroll
        for (int j = 0; j < 8; ++j) {
            int p = dot4i8(q.x, x[j].x, 0);
            p     = dot4i8(q.y, x[j].y, p);
            p += __shfl_xor(p, 1);
            p += __shfl_xor(p, 2);
            p += __shfl_xor(p, 4);
            const float f = (float)p * s2[j];   // 0 for masked slots
            const int32_t wx = (int32_t)x[j].x, wy = (int32_t)x[j].y;
            acc[0] = fmaf(f, (float)((wx << 24) >> 24), acc[0]);
            acc[1] = fmaf(f, (float)((wx << 16) >> 24), acc[1]);
            acc[2] = fmaf(f, (float)((wx <<  8) >> 24), acc[2]);
            acc[3] = fmaf(f, (float)( wx        >> 24), acc[3]);
            acc[4] = fmaf(f, (float)((wy << 24) >> 24), acc[4]);
            acc[5] = fmaf(f, (float)((wy << 16) >> 24), acc[5]);
            acc[6] = fmaf(f, (float)((wy <<  8) >> 24), acc[6]);
            acc[7] = fmaf(f, (float)( wy        >> 24), acc[7]);
        }
        base += 8;
    }

    const float k = scales[node] * aw[0];
    float* o = &out[(size_t)node * OUT_DIM + sl * 8];
    *(float4*)&o[0] = make_float4(acc[0]*k, acc[1]*k, acc[2]*k, acc[3]*k);
    *(float4*)&o[4] = make_float4(acc[4]*k, acc[5]*k, acc[6]*k, acc[7]*k);
}

// ---------------------------------------------------------------------------
extern "C" void kernel_launch(void* const* d_in, const int* in_sizes, int n_in,
                              void* d_out, int out_size, void* d_ws, size_t ws_size,
                              hipStream_t stream) {
    const float* X   = (const float*)d_in[0];
    const float* W   = (const float*)d_in[1];
    const float* aw  = (const float*)d_in[2];
    const int*   src = (const int*)d_in[3];
    const int*   dst = (const int*)d_in[4];
    float* out = (float*)d_out;

    // ws layout (bytes):
    //   Q       @ 0          6,400,000  (int8 N*64)
    //   scales  @ 6,400,000    400,000  (f32 N)
    //   row_ptr @ 6,800,000    400,004
    //   Wfrag   @ 7,200,016     16,384   -> end 7,216,400
    uint8_t* Q       = (uint8_t*)d_ws;
    float*   scales  = (float*)((char*)d_ws + 6400000);
    int*     row_ptr = (int*)((char*)d_ws + 6800000);
    uint4*   Wfrag   = (uint4*)((char*)d_ws + 7200016);

    prep<<<N_EDGES / 256 + 4, 256, 0, stream>>>(src, W, row_ptr, Wfrag);
    gemm_q<<<(N_NODES + 63) / 64, 256, 0, stream>>>(X, Wfrag, Q, scales, N_NODES);
    agnn_edge_q<<<N_NODES / 32, 256, 0, stream>>>(Q, scales, row_ptr, dst, aw, out);
}

// Round 10
// 58.017 us; speedup vs baseline: 1.0998x; 1.0998x over previous
//
#include <hip/hip_runtime.h>
#include <stdint.h>

#define N_NODES 100000
#define N_EDGES 1600000
#define IN_DIM 128
#define OUT_DIM 64

typedef __bf16    bf16x8 __attribute__((ext_vector_type(8)));
typedef float     f32x4  __attribute__((ext_vector_type(4)));

__device__ __forceinline__ uint16_t f2bf(float f) {   // RNE
    uint32_t u = __float_as_uint(f);
    return (uint16_t)((u + 0x7fffu + ((u >> 16) & 1u)) >> 16);
}
__device__ __forceinline__ int dot4i8(uint32_t a, uint32_t b, int c) {
#if __has_builtin(__builtin_amdgcn_sdot4)
    return __builtin_amdgcn_sdot4((int)a, (int)b, c, false);
#else
    #pragma unroll
    for (int k = 0; k < 4; ++k)
        c += (int)(int8_t)(a >> (8 * k)) * (int)(int8_t)(b >> (8 * k));
    return c;
#endif
}

// ---------------------------------------------------------------------------
// prep (R8-proven): blocks [0,6250) build row_ptr from sorted edge_src;
// blocks [6250,6254) pack W into per-lane MFMA B-fragments.
// ---------------------------------------------------------------------------
__global__ __launch_bounds__(256) void prep(const int* __restrict__ src,
                                            const float* __restrict__ W,
                                            int* __restrict__ row_ptr,
                                            uint4* __restrict__ Wfrag) {
    const int b = blockIdx.x;
    if (b < N_EDGES / 256) {
        int e = b * 256 + threadIdx.x;
        int s = src[e];
        if (e == 0) {
            for (int i = 0; i <= s; ++i) row_ptr[i] = 0;
        } else {
            int sp = src[e - 1];
            for (int i = sp + 1; i <= s; ++i) row_ptr[i] = e;
        }
        if (e == N_EDGES - 1) {
            for (int i = s + 1; i <= N_NODES; ++i) row_ptr[i] = N_EDGES;
        }
    } else {
        int item = (b - N_EDGES / 256) * 256 + threadIdx.x;   // 0..1023
        if (item < 1024) {
            int f = item >> 6, lane = item & 63;
            int ct = f >> 2, ks = f & 3;
            int col = ct * 16 + (lane & 15);
            int kb  = ks * 32 + (lane >> 4) * 8;
            uint32_t u[4];
            #pragma unroll
            for (int j = 0; j < 4; ++j) {
                uint32_t lo = f2bf(W[(kb + 2 * j)     * OUT_DIM + col]);
                uint32_t hi = f2bf(W[(kb + 2 * j + 1) * OUT_DIM + col]);
                u[j] = lo | (hi << 16);
            }
            Wfrag[f * 64 + lane] = make_uint4(u[0], u[1], u[2], u[3]);
        }
    }
}

// ---------------------------------------------------------------------------
// GEMM + fused per-row int8 quantization (R8-proven). X@W via
// mfma_f32_16x16x32_bf16; per-row max via 16-lane shfl reduce;
// Q[row] = int8(acc * 127/rowmax), scales[row] = rowmax/127.
// ---------------------------------------------------------------------------
__global__ __launch_bounds__(256) void gemm_q(const float* __restrict__ X,
                                              const uint4* __restrict__ Wfrag,
                                              uint8_t* __restrict__ Q,
                                              float* __restrict__ scales,
                                              int nRows) {
    const int t = threadIdx.x;
    const int lane = t & 63;

    bf16x8 bfr[16];
    #pragma unroll
    for (int f = 0; f < 16; ++f)
        bfr[f] = __builtin_bit_cast(bf16x8, Wfrag[f * 64 + lane]);

    const int rowBase = blockIdx.x * 64 + (t >> 6) * 16;
    const int r  = rowBase + (lane & 15);
    const int kb = (lane >> 4) * 8;
    const bool inb = r < nRows;

    f32x4 acc[4] = {{0,0,0,0},{0,0,0,0},{0,0,0,0},{0,0,0,0}};

    #pragma unroll
    for (int ks = 0; ks < 4; ++ks) {
        float4 x0 = make_float4(0.f,0.f,0.f,0.f), x1 = x0;
        if (inb) {
            const float* p = &X[(size_t)r * IN_DIM + ks * 32 + kb];
            x0 = *(const float4*)&p[0];
            x1 = *(const float4*)&p[4];
        }
        bf16x8 a;
        a[0]=(__bf16)x0.x; a[1]=(__bf16)x0.y; a[2]=(__bf16)x0.z; a[3]=(__bf16)x0.w;
        a[4]=(__bf16)x1.x; a[5]=(__bf16)x1.y; a[6]=(__bf16)x1.z; a[7]=(__bf16)x1.w;
        #pragma unroll
        for (int ct = 0; ct < 4; ++ct)
            acc[ct] = __builtin_amdgcn_mfma_f32_16x16x32_bf16(a, bfr[ct * 4 + ks], acc[ct], 0, 0, 0);
    }

    // Epilogue. C/D layout: col = ct*16 + (lane&15), row = orow + rr.
    const int orow = rowBase + (lane >> 4) * 4;
    const int ocol = lane & 15;
    #pragma unroll
    for (int rr = 0; rr < 4; ++rr) {
        float m = fmaxf(fmaxf(fabsf(acc[0][rr]), fabsf(acc[1][rr])),
                        fmaxf(fabsf(acc[2][rr]), fabsf(acc[3][rr])));
        m = fmaxf(m, __shfl_xor(m, 1));
        m = fmaxf(m, __shfl_xor(m, 2));
        m = fmaxf(m, __shfl_xor(m, 4));
        m = fmaxf(m, __shfl_xor(m, 8));       // row max over 16 lanes
        const float inv = m > 0.f ? 127.f / m : 0.f;
        const int gr = orow + rr;
        if (gr < nRows) {
            if (ocol == 0) scales[gr] = m * (1.f / 127.f);
            #pragma unroll
            for (int ct = 0; ct < 4; ++ct) {
                int v = (int)rintf(acc[ct][rr] * inv);
                v = min(127, max(-127, v));
                Q[(size_t)gr * OUT_DIM + ct * 16 + ocol] = (uint8_t)(int8_t)v;
            }
        }
    }
}

// ---------------------------------------------------------------------------
// Edge kernel (int8, per-row scales): R8's proven single-buffer loop +
// two minimal deltas: (a) ONE own-slot scale gather per edge (distributed by
// shfl; masked source lanes hold ms=0, identical masking semantics to R8's
// per-slot s2=0), (b) cross-chunk prefetch of next chunk's dst+scale so the
// row-gathers never wait on a fresh index load (R7-proven pattern).
// ---------------------------------------------------------------------------
__global__ __launch_bounds__(256, 8) void agnn_edge_q(const uint8_t* __restrict__ Q,
                                                      const float* __restrict__ scales,
                                                      const int* __restrict__ row_ptr,
                                                      const int* __restrict__ dst,
                                                      const float* __restrict__ aw,
                                                      float* __restrict__ out) {
    const int t    = threadIdx.x;
    const int lane = t & 63;
    const int g    = lane >> 3;
    const int sl   = lane & 7;
    const int node = blockIdx.x * 32 + (t >> 6) * 8 + g;

    const int lo = row_ptr[node];
    const int hi = row_ptr[node + 1];

    const uint2 q = *(const uint2*)&Q[(size_t)node * OUT_DIM + sl * 8];
    float acc[8] = {0.f,0.f,0.f,0.f,0.f,0.f,0.f,0.f};

    int   base = lo;
    int   myd  = 0;
    float ms   = 0.f;
    if (base + sl < hi) {
        myd = dst[base + sl];           // coalesced per group
        ms  = scales[myd];              // own-slot gather (1 per edge)
    }

    while (__any(base < hi)) {
        // prefetch next chunk's indices + scales (off the critical path)
        const int base2 = base + 8;
        int   myd2 = 0;
        float ms2  = 0.f;
        if (base2 + sl < hi) {
            myd2 = dst[base2 + sl];
            ms2  = scales[myd2];
        }

        const int nj = hi - base;       // group-uniform; <=0 when group done
        const float msq = ms * ms;

        uint2 x[8];
        #pragma unroll
        for (int j = 0; j < 8; ++j) {
            x[j] = make_uint2(0u, 0u);
            if (j < nj) {               // exec-masked: no traffic when done
                const int dj = __shfl(myd, g * 8 + j);
                x[j] = *(const uint2*)&Q[(size_t)dj * OUT_DIM + sl * 8];
            }
        }
        #pragma unroll
        for (int j = 0; j < 8; ++j) {
            int p = dot4i8(q.x, x[j].x, 0);
            p     = dot4i8(q.y, x[j].y, p);
            p += __shfl_xor(p, 1);
            p += __shfl_xor(p, 2);
            p += __shfl_xor(p, 4);
            const float tj = __shfl(msq, g * 8 + j);   // 0 for masked slots
            const float f  = (float)p * tj;
            const int32_t wx = (int32_t)x[j].x, wy = (int32_t)x[j].y;
            acc[0] = fmaf(f, (float)((wx << 24) >> 24), acc[0]);
            acc[1] = fmaf(f, (float)((wx << 16) >> 24), acc[1]);
            acc[2] = fmaf(f, (float)((wx <<  8) >> 24), acc[2]);
            acc[3] = fmaf(f, (float)( wx        >> 24), acc[3]);
            acc[4] = fmaf(f, (float)((wy << 24) >> 24), acc[4]);
            acc[5] = fmaf(f, (float)((wy << 16) >> 24), acc[5]);
            acc[6] = fmaf(f, (float)((wy <<  8) >> 24), acc[6]);
            acc[7] = fmaf(f, (float)( wy        >> 24), acc[7]);
        }
        base = base2;
        myd  = myd2;
        ms   = ms2;
    }

    const float k = scales[node] * aw[0];
    float* o = &out[(size_t)node * OUT_DIM + sl * 8];
    *(float4*)&o[0] = make_float4(acc[0]*k, acc[1]*k, acc[2]*k, acc[3]*k);
    *(float4*)&o[4] = make_float4(acc[4]*k, acc[5]*k, acc[6]*k, acc[7]*k);
}

// ---------------------------------------------------------------------------
extern "C" void kernel_launch(void* const* d_in, const int* in_sizes, int n_in,
                              void* d_out, int out_size, void* d_ws, size_t ws_size,
                              hipStream_t stream) {
    const float* X   = (const float*)d_in[0];
    const float* W   = (const float*)d_in[1];
    const float* aw  = (const float*)d_in[2];
    const int*   src = (const int*)d_in[3];
    const int*   dst = (const int*)d_in[4];
    float* out = (float*)d_out;

    // ws layout (bytes):
    //   Q       @ 0          6,400,000  (int8 N*64)
    //   scales  @ 6,400,000    400,000  (f32 N)
    //   row_ptr @ 6,800,000    400,004
    //   Wfrag   @ 7,200,016     16,384   -> end 7,216,400
    uint8_t* Q       = (uint8_t*)d_ws;
    float*   scales  = (float*)((char*)d_ws + 6400000);
    int*     row_ptr = (int*)((char*)d_ws + 6800000);
    uint4*   Wfrag   = (uint4*)((char*)d_ws + 7200016);

    prep<<<N_EDGES / 256 + 4, 256, 0, stream>>>(src, W, row_ptr, Wfrag);
    gemm_q<<<(N_NODES + 63) / 64, 256, 0, stream>>>(X, Wfrag, Q, scales, N_NODES);
    agnn_edge_q<<<N_NODES / 32, 256, 0, stream>>>(Q, scales, row_ptr, dst, aw, out);
}